// Round 8
// baseline (330.837 us; speedup 1.0000x reference)
//
#include <hip/hip_runtime.h>

typedef _Float16 f16;
typedef _Float16 f16x4 __attribute__((ext_vector_type(4)));
typedef _Float16 f16x8 __attribute__((ext_vector_type(8)));
typedef float    f32x4 __attribute__((ext_vector_type(4)));

#define B_ 4
#define C_ 512
#define N_ 4096
#define M_ 64

// ---------------------------------------------------------------------------
// Kernel T: x [B][C][N] fp32 -> xtf in qkv B-FRAGMENT ORDER (round-7, valid):
//   xtf[b][nt(256)][ck(16)][lane(64)][jj(8)], n = nt*16 + (lane&15),
//   c = ck*32 + (lane>>4)*8 + jj.
// ---------------------------------------------------------------------------
__global__ __launch_bounds__(256) void transpose_cast(
    const float* __restrict__ x, f16* __restrict__ xtf)
{
    __shared__ float sT[64][65];
    const int n0 = blockIdx.x * 64;
    const int c0 = blockIdx.y * 64;
    const int b  = blockIdx.z;
    const int tid = threadIdx.x;

    #pragma unroll
    for (int i = 0; i < 4; ++i) {
        int e = i * 256 + tid;
        int c = e >> 4;
        int n4 = (e & 15) * 4;
        float4 v = *(const float4*)(x + ((size_t)(b * C_ + c0 + c)) * N_ + n0 + n4);
        sT[c][n4 + 0] = v.x; sT[c][n4 + 1] = v.y;
        sT[c][n4 + 2] = v.z; sT[c][n4 + 3] = v.w;
    }
    __syncthreads();

    const int w = tid >> 6, lane = tid & 63, l15 = lane & 15, quad = lane >> 4;
    #pragma unroll
    for (int j = 0; j < 2; ++j) {
        const int fb  = w * 2 + j;
        const int lnt = fb >> 1, lck = fb & 1;
        const int nl  = lnt * 16 + l15;
        const int cb  = lck * 32 + quad * 8;
        f16x8 o;
        #pragma unroll
        for (int jj = 0; jj < 8; ++jj) o[jj] = (f16)sT[cb + jj][nl];
        const int ntg = (n0 >> 4) + lnt;
        const int ck  = (c0 >> 5) + lck;
        size_t idx = (((size_t)(b * 256 + ntg)) * 16 + ck) * 512 + lane * 8;
        *(f16x8*)(xtf + idx) = o;
    }
}

// ---------------------------------------------------------------------------
// Kernel A: fused qkv GEMM (round-7, validated). ONE change: q is prescaled
// by log2(e) so attn can use exp2 directly (qt's only consumer is scores).
// ---------------------------------------------------------------------------
__global__ __launch_bounds__(512) void qkv_gemm(
    const f16* __restrict__ xtf,
    const float* __restrict__ Wq, const float* __restrict__ bq,
    const float* __restrict__ Wk, const float* __restrict__ bk,
    const float* __restrict__ Wv, const float* __restrict__ bv,
    f16* __restrict__ qt, f16* __restrict__ ktf, f16* __restrict__ vf)
{
    const int tid  = threadIdx.x;
    const int w    = tid >> 6;
    const int lane = tid & 63;
    const int l15  = lane & 15;
    const int quad = lane >> 4;
    const int nBase = blockIdx.x * 128;
    const int oseg  = blockIdx.y;
    const int b     = blockIdx.z;
    const int ot16  = w & 3;
    const int nhalf = w >> 2;

    const float* Wsel;
    if (oseg == 0)      Wsel = Wq;
    else if (oseg == 1) Wsel = Wk;
    else                Wsel = Wv + (size_t)(oseg - 2) * 64 * C_;

    const int orow = ot16 * 16 + l15;
    const float* wp = Wsel + (size_t)orow * C_ + quad * 8;

    const f16* xfb[4];
    #pragma unroll
    for (int ns = 0; ns < 4; ++ns) {
        int ntg = (nBase >> 4) + nhalf * 4 + ns;
        xfb[ns] = xtf + (((size_t)(b * 256 + ntg)) * 16) * 512 + lane * 8;
    }

    f32x4 acc[4] = {};

    float4 w0c = *(const float4*)(wp);
    float4 w1c = *(const float4*)(wp + 4);
    f16x8 b8c[4];
    #pragma unroll
    for (int ns = 0; ns < 4; ++ns) b8c[ns] = *(const f16x8*)(xfb[ns]);

    for (int ck = 0; ck < 16; ++ck) {
        float4 w0n, w1n;
        f16x8  b8n[4];
        if (ck + 1 < 16) {
            w0n = *(const float4*)(wp + ck * 32 + 32);
            w1n = *(const float4*)(wp + ck * 32 + 36);
            #pragma unroll
            for (int ns = 0; ns < 4; ++ns)
                b8n[ns] = *(const f16x8*)(xfb[ns] + (ck + 1) * 512);
        }
        f16x8 a8;
        a8[0]=(f16)w0c.x; a8[1]=(f16)w0c.y; a8[2]=(f16)w0c.z; a8[3]=(f16)w0c.w;
        a8[4]=(f16)w1c.x; a8[5]=(f16)w1c.y; a8[6]=(f16)w1c.z; a8[7]=(f16)w1c.w;
        #pragma unroll
        for (int ns = 0; ns < 4; ++ns)
            acc[ns] = __builtin_amdgcn_mfma_f32_16x16x32_f16(a8, b8c[ns], acc[ns], 0, 0, 0);
        w0c = w0n; w1c = w1n;
        #pragma unroll
        for (int ns = 0; ns < 4; ++ns) b8c[ns] = b8n[ns];
    }

    #pragma unroll
    for (int ns = 0; ns < 4; ++ns) {
        int n = nBase + nhalf * 64 + ns * 16 + l15;
        #pragma unroll
        for (int r = 0; r < 4; ++r) {
            int olocal = ot16 * 16 + quad * 4 + r;
            float bias;
            if (oseg == 0)      bias = bq[olocal];
            else if (oseg == 1) bias = bk[olocal];
            else                bias = bv[(oseg - 2) * 64 + olocal];
            if (oseg == 0) {
                // log2(e) prescale: scores come out in base-2 -> exp2 in attn
                f16 h = (f16)((acc[ns][r] + bias) * 1.4426950408889634f);
                qt[((size_t)(b * N_ + n)) * M_ + olocal] = h;
            } else if (oseg == 1) {
                f16 h = (f16)(acc[ns][r] + bias);
                size_t idx = (((size_t)b * 256 + (n >> 4)) * 2 + (olocal >> 5)) * 512
                           + (size_t)((((olocal >> 3) & 3) * 16 + (n & 15)) * 8) + (olocal & 7);
                ktf[idx] = h;
            } else {
                f16 h = (f16)(acc[ns][r] + bias);
                int c = (oseg - 2) * 64 + olocal;
                size_t idx = ((size_t)b * (C_ * N_)) + (size_t)(c >> 4) * 65536
                           + (size_t)(n >> 6) * 1024 + (size_t)((n >> 5) & 1) * 512
                           + (size_t)((((n >> 3) & 3) * 16 + (c & 15)) * 8) + (n & 7);
                vf[idx] = h;
            }
        }
    }
}

// ---------------------------------------------------------------------------
// Kernel B: barrier-free fused attention (round-6 structure). Round-8:
//  (1) pass-1 rowmax j-split 4x across waves + ONE __syncthreads + LDS combine
//  (2) exp2f on log2e-prescaled scores (one v_exp, no v_mul)
//  (3) wave-private LDS scratch for P C->B-frag transform (8x ds_write_b64 +
//      4x ds_read_b128, same-wave ordering, NO barrier) replaces 32 bpermute.
// ---------------------------------------------------------------------------
__global__ __launch_bounds__(256, 2) void attn(
    const f16* __restrict__ qt, const f16* __restrict__ ktf,
    const f16* __restrict__ vf, const float* __restrict__ x,
    const float* __restrict__ gamma, float* __restrict__ out)
{
    __shared__ __align__(16) f16 sPw[4][32][72];   // per-wave scratch, 18.4 KB
    __shared__ float sRm[4][2][16];

    const int tid  = threadIdx.x;
    const int w    = tid >> 6;                  // 0..3
    const int lane = tid & 63;
    const int l15  = lane & 15;
    const int quad = lane >> 4;

    const int lin  = blockIdx.x;                // 0..511
    const int b    = (lin & 7) >> 1;
    const int iblk = ((lin >> 3) << 1) | (lin & 1);
    const int i0   = iblk * 32;
    const int ctg0 = w * 8;

    const f16* kln = ktf + (size_t)b * (N_ * M_) + lane * 8;
    const f16* vln = vf  + (size_t)b * (C_ * N_) + lane * 8;

    f16x8 bqf[2][2];
    #pragma unroll
    for (int is = 0; is < 2; ++is)
        #pragma unroll
        for (int kh = 0; kh < 2; ++kh)
            bqf[is][kh] = *(const f16x8*)(qt + ((size_t)(b * N_ + i0 + is * 16 + l15)) * M_
                                          + kh * 32 + quad * 8);

    // -------- pass 1: rowmax, j-split: wave w scans j in [w*1024, w*1024+1024)
    float mx0 = -3.0e38f, mx1 = -3.0e38f;
    {
        const f16* kw = kln + (size_t)w * 65536;   // w*1024 j -> w*64 tiles
        f16x8 akc[4][2];
        #pragma unroll
        for (int jt = 0; jt < 4; ++jt)
            #pragma unroll
            for (int kh = 0; kh < 2; ++kh)
                akc[jt][kh] = *(const f16x8*)(kw + (size_t)jt * 1024 + kh * 512);

        for (int it = 0; it < 16; ++it) {
            f16x8 akn[4][2];
            if (it + 1 < 16) {
                const f16* kn = kw + (size_t)(it + 1) * 4096;
                #pragma unroll
                for (int jt = 0; jt < 4; ++jt)
                    #pragma unroll
                    for (int kh = 0; kh < 2; ++kh)
                        akn[jt][kh] = *(const f16x8*)(kn + (size_t)jt * 1024 + kh * 512);
            }
            #pragma unroll
            for (int jt = 0; jt < 4; ++jt) {
                f32x4 s0 = {}, s1 = {};
                s0 = __builtin_amdgcn_mfma_f32_16x16x32_f16(akc[jt][0], bqf[0][0], s0, 0, 0, 0);
                s0 = __builtin_amdgcn_mfma_f32_16x16x32_f16(akc[jt][1], bqf[0][1], s0, 0, 0, 0);
                s1 = __builtin_amdgcn_mfma_f32_16x16x32_f16(akc[jt][0], bqf[1][0], s1, 0, 0, 0);
                s1 = __builtin_amdgcn_mfma_f32_16x16x32_f16(akc[jt][1], bqf[1][1], s1, 0, 0, 0);
                mx0 = fmaxf(mx0, fmaxf(fmaxf(s0[0], s0[1]), fmaxf(s0[2], s0[3])));
                mx1 = fmaxf(mx1, fmaxf(fmaxf(s1[0], s1[1]), fmaxf(s1[2], s1[3])));
            }
            #pragma unroll
            for (int jt = 0; jt < 4; ++jt)
                #pragma unroll
                for (int kh = 0; kh < 2; ++kh)
                    akc[jt][kh] = akn[jt][kh];
        }
    }
    mx0 = fmaxf(mx0, __shfl_xor(mx0, 16, 64));
    mx0 = fmaxf(mx0, __shfl_xor(mx0, 32, 64));
    mx1 = fmaxf(mx1, __shfl_xor(mx1, 16, 64));
    mx1 = fmaxf(mx1, __shfl_xor(mx1, 32, 64));
    if (lane < 16) { sRm[w][0][lane] = mx0; sRm[w][1][lane] = mx1; }
    __syncthreads();   // the ONLY block-wide barrier in the kernel
    const float mrow0 = fmaxf(fmaxf(sRm[0][0][l15], sRm[1][0][l15]),
                              fmaxf(sRm[2][0][l15], sRm[3][0][l15]));
    const float mrow1 = fmaxf(fmaxf(sRm[0][1][l15], sRm[1][1][l15]),
                              fmaxf(sRm[2][1][l15], sRm[3][1][l15]));

    // -------- pass 2: P + PV (full j range per wave) --------
    f32x4 acc[8][2] = {};
    float l0 = 0.f, l1 = 0.f;

    f16x8 akc[4][2];
    #pragma unroll
    for (int jt = 0; jt < 4; ++jt)
        #pragma unroll
        for (int kh = 0; kh < 2; ++kh)
            akc[jt][kh] = *(const f16x8*)(kln + (size_t)jt * 1024 + kh * 512);

    #pragma unroll 2
    for (int j0 = 0; j0 < N_; j0 += 64) {
        const f16* vt = vln + (size_t)(j0 >> 6) * 1024;
        f16x8 vb0[8];
        #pragma unroll
        for (int ct = 0; ct < 8; ++ct)
            vb0[ct] = *(const f16x8*)(vt + (size_t)(ctg0 + ct) * 65536);
        f16x8 akn[4][2];
        if (j0 + 64 < N_) {
            const f16* kn = kln + (size_t)(j0 + 64) * 64;
            #pragma unroll
            for (int jt = 0; jt < 4; ++jt)
                #pragma unroll
                for (int kh = 0; kh < 2; ++kh)
                    akn[jt][kh] = *(const f16x8*)(kn + (size_t)jt * 1024 + kh * 512);
        }

        // scores -> p via exp2 (q prescaled by log2e) -> wave-private LDS
        #pragma unroll
        for (int jt = 0; jt < 4; ++jt) {
            f32x4 s0 = {}, s1 = {};
            s0 = __builtin_amdgcn_mfma_f32_16x16x32_f16(akc[jt][0], bqf[0][0], s0, 0, 0, 0);
            s0 = __builtin_amdgcn_mfma_f32_16x16x32_f16(akc[jt][1], bqf[0][1], s0, 0, 0, 0);
            s1 = __builtin_amdgcn_mfma_f32_16x16x32_f16(akc[jt][0], bqf[1][0], s1, 0, 0, 0);
            s1 = __builtin_amdgcn_mfma_f32_16x16x32_f16(akc[jt][1], bqf[1][1], s1, 0, 0, 0);
            f16x4 p4, q4;
            #pragma unroll
            for (int r = 0; r < 4; ++r) {
                float p = exp2f(s0[r] - mrow0);
                float q = exp2f(s1[r] - mrow1);
                l0 += p; l1 += q;
                p4[r] = (f16)p; q4[r] = (f16)q;
            }
            *(f16x4*)&sPw[w][l15]     [jt * 16 + quad * 4] = p4;
            *(f16x4*)&sPw[w][16 + l15][jt * 16 + quad * 4] = q4;
        }

        // C-layout -> B-frag via same-wave LDS round-trip (no barrier)
        f16x8 pbf[2][2];
        #pragma unroll
        for (int is = 0; is < 2; ++is)
            #pragma unroll
            for (int kh = 0; kh < 2; ++kh)
                pbf[is][kh] = *(const f16x8*)&sPw[w][is * 16 + l15][kh * 32 + quad * 8];

        f16x8 vb1[8];
        #pragma unroll
        for (int ct = 0; ct < 8; ++ct)
            vb1[ct] = *(const f16x8*)(vt + (size_t)(ctg0 + ct) * 65536 + 512);

        #pragma unroll
        for (int ct = 0; ct < 8; ++ct) {
            acc[ct][0] = __builtin_amdgcn_mfma_f32_16x16x32_f16(vb0[ct], pbf[0][0], acc[ct][0], 0, 0, 0);
            acc[ct][1] = __builtin_amdgcn_mfma_f32_16x16x32_f16(vb0[ct], pbf[1][0], acc[ct][1], 0, 0, 0);
        }
        #pragma unroll
        for (int ct = 0; ct < 8; ++ct) {
            acc[ct][0] = __builtin_amdgcn_mfma_f32_16x16x32_f16(vb1[ct], pbf[0][1], acc[ct][0], 0, 0, 0);
            acc[ct][1] = __builtin_amdgcn_mfma_f32_16x16x32_f16(vb1[ct], pbf[1][1], acc[ct][1], 0, 0, 0);
        }

        #pragma unroll
        for (int jt = 0; jt < 4; ++jt)
            #pragma unroll
            for (int kh = 0; kh < 2; ++kh)
                akc[jt][kh] = akn[jt][kh];
    }

    l0 += __shfl_xor(l0, 16, 64);
    l0 += __shfl_xor(l0, 32, 64);
    l1 += __shfl_xor(l1, 16, 64);
    l1 += __shfl_xor(l1, 32, 64);

    const float g = gamma[0];
    const float linv0 = 1.0f / l0, linv1 = 1.0f / l1;
    #pragma unroll
    for (int is = 0; is < 2; ++is) {
        const float li = is ? linv1 : linv0;
        const int i = i0 + is * 16 + l15;
        #pragma unroll
        for (int ct = 0; ct < 8; ++ct) {
            #pragma unroll
            for (int r = 0; r < 4; ++r) {
                const int c = (ctg0 + ct) * 16 + quad * 4 + r;
                const size_t idx = ((size_t)(b * C_ + c)) * N_ + i;
                out[idx] = g * (acc[ct][is][r] * li) + x[idx];
            }
        }
    }
}

// ---------------------------------------------------------------------------
extern "C" void kernel_launch(void* const* d_in, const int* in_sizes, int n_in,
                              void* d_out, int out_size, void* d_ws, size_t ws_size,
                              hipStream_t stream)
{
    const float* x     = (const float*)d_in[0];
    const float* Wq    = (const float*)d_in[1];
    const float* bq    = (const float*)d_in[2];
    const float* Wk    = (const float*)d_in[3];
    const float* bk    = (const float*)d_in[4];
    const float* Wv    = (const float*)d_in[5];
    const float* bv    = (const float*)d_in[6];
    const float* gamma = (const float*)d_in[7];
    float* out = (float*)d_out;

    char* ws = (char*)d_ws;
    f16* xtf = (f16*)ws;                                   // B*N*C   (16 MB)
    f16* qt  = (f16*)(ws + (size_t)B_ * N_ * C_ * 2);      // B*N*M   ( 2 MB)
    f16* ktf = qt + (size_t)B_ * N_ * M_;                  // B*N*M   ( 2 MB)
    f16* vf  = ktf + (size_t)B_ * N_ * M_;                 // B*C*N   (16 MB)

    transpose_cast<<<dim3(N_ / 64, C_ / 64, B_), 256, 0, stream>>>(x, xtf);
    qkv_gemm<<<dim3(N_ / 128, 10, B_), 512, 0, stream>>>(
        xtf, Wq, bq, Wk, bk, Wv, bv, qt, ktf, vf);
    attn<<<dim3(512), 256, 0, stream>>>(qt, ktf, vf, x, gamma, out);
}